// Round 1
// baseline (658.170 us; speedup 1.0000x reference)
//
#include <hip/hip_runtime.h>
#include <math.h>

// SVDObserver: x (64,512,64,64) f32, w_proj (24,512) f32, ema_s (24) f32
// outputs (flat f32 concat): S (64,24) | Vh (64,24,24) | features (64,50) | novelty (64,24)
//
// Strategy:
//  K1 proj_gram: h[b,n,:] = W x[b,:,n]; per-WG partial Gram (fp64 accum, fixed order).
//  K2 gram_reduce: sum 16 partials -> G (64,24,24) fp32.
//  K3 eigh_feat: faithful fp32 port of LAPACK ssyevd path for n=24:
//       ssytd2 (lower) -> ssteqr('I') -> sormtr -> selection sort (inside ssteqr)
//     This matches np.linalg.eigh's eigenvector SIGNS (they are algorithm-defined).
//     slartg: LAPACK >=3.10 convention (c=|f|/d>=0). If Vh ever fails with
//     +-2|v| column sign flips, switch USE_NEW_SLARTG to 0 (pre-3.10 convention).

#define USE_NEW_SLARTG 1
#define N24 24

// ---------------------------------------------------------------- K1
__global__ __launch_bounds__(256) void proj_gram_kernel(
    const float* __restrict__ x, const float* __restrict__ w,
    double* __restrict__ partial)
{
    const int b    = blockIdx.x >> 4;
    const int tile = blockIdx.x & 15;
    const int tid  = threadIdx.x;
    const int n0   = (tile << 8) | tid;           // pixel index within 4096
    __shared__ __align__(16) float wl[24 * 512];  // 48 KB
    for (int i2 = tid; i2 < 24 * 512; i2 += 256) wl[i2] = w[i2];
    __syncthreads();

    const float* xb = x + ((size_t)b << 21) + n0; // b*512*4096 + n
    float h[24];
#pragma unroll
    for (int k = 0; k < 24; ++k) h[k] = 0.f;
    for (int c = 0; c < 512; c += 4) {
        float x0 = xb[(size_t)(c + 0) << 12];
        float x1 = xb[(size_t)(c + 1) << 12];
        float x2 = xb[(size_t)(c + 2) << 12];
        float x3 = xb[(size_t)(c + 3) << 12];
#pragma unroll
        for (int k = 0; k < 24; ++k) {
            const float4 wv = *reinterpret_cast<const float4*>(&wl[k * 512 + c]);
            h[k] += wv.x * x0 + wv.y * x1 + wv.z * x2 + wv.w * x3;
        }
    }
    __syncthreads();           // everyone done reading wl
    float* hl = wl;            // reuse LDS: 256*24 floats
#pragma unroll
    for (int k = 0; k < 24; ++k) hl[tid * 24 + k] = h[k];
    __syncthreads();

    // 300 unique pairs (k<=m), fp64 accumulation over this WG's 256 pixels
    for (int p = tid; p < 300; p += 256) {
        int k = 0, pp = p;
        while (pp >= 24 - k) { pp -= 24 - k; ++k; }
        int m = k + pp;
        double acc = 0.0;
        for (int i2 = 0; i2 < 256; ++i2)
            acc += (double)hl[i2 * 24 + k] * (double)hl[i2 * 24 + m];
        partial[(size_t)blockIdx.x * 300 + p] = acc;
    }
}

// ---------------------------------------------------------------- K2
__global__ __launch_bounds__(320) void gram_reduce_kernel(
    const double* __restrict__ partial, float* __restrict__ G)
{
    const int b = blockIdx.x;
    const int p = threadIdx.x;
    if (p >= 300) return;
    int k = 0, pp = p;
    while (pp >= 24 - k) { pp -= 24 - k; ++k; }
    int m = k + pp;
    double acc = 0.0;
    for (int t = 0; t < 16; ++t)
        acc += partial[((size_t)(b * 16 + t)) * 300 + p];
    float v = (float)acc;
    G[b * 576 + k * 24 + m] = v;
    G[b * 576 + m * 24 + k] = v;   // exactly symmetric
}

// ------------------------------------------------------- LAPACK helpers
__device__ __forceinline__ float lapy2f(float xx, float yy) {
#pragma clang fp contract(off)
    float xa = fabsf(xx), ya = fabsf(yy);
    float w = fmaxf(xa, ya), z = fminf(xa, ya);
    if (z == 0.f) return w;
    float q = z / w;
    return w * sqrtf(1.f + q * q);
}

__device__ __forceinline__ void slartg_(float f, float g, float& c, float& s, float& r) {
#pragma clang fp contract(off)
#if USE_NEW_SLARTG
    if (g == 0.f) { c = 1.f; s = 0.f; r = f; }
    else if (f == 0.f) { c = 0.f; s = copysignf(1.f, g); r = fabsf(g); }
    else {
        float f1 = fabsf(f), g1 = fabsf(g);
        const float rtmin_ = 0x1p-63f;          // sqrt(safmin)
        const float rtmax_ = 1.8446743e+19f;    // ~sqrt(safmax)
        float d, p;
        if (f1 > rtmin_ && f1 < rtmax_ && g1 > rtmin_ && g1 < rtmax_) {
            d = sqrtf(f * f + g * g);
            p = 1.f / d;
            c = f1 * p;
            s = g * copysignf(p, f);
            r = copysignf(d, f);
        } else {
            float u = fminf(3.4028235e+38f, fmaxf(0x1p-126f, fmaxf(f1, g1)));
            float fs = f / u, gs = g / u;
            d = sqrtf(fs * fs + gs * gs);
            p = 1.f / d;
            c = fabsf(fs) * p;
            s = gs * copysignf(p, f);
            r = copysignf(d, f) * u;
        }
    }
#else
    if (g == 0.f) { c = 1.f; s = 0.f; r = f; }
    else if (f == 0.f) { c = 0.f; s = 1.f; r = g; }
    else {
        float rr = sqrtf(f * f + g * g);
        c = f / rr; s = g / rr; r = rr;
        if (fabsf(f) > fabsf(g) && c < 0.f) { c = -c; s = -s; r = -r; }
    }
#endif
}

__device__ __forceinline__ void slaev2_(float a, float b, float cc,
                                        float& rt1, float& rt2, float& cs1, float& sn1) {
#pragma clang fp contract(off)
    float sm = a + cc, df = a - cc, adf = fabsf(df);
    float tb = b + b, ab = fabsf(tb);
    float acmx, acmn;
    if (fabsf(a) > fabsf(cc)) { acmx = a; acmn = cc; } else { acmx = cc; acmn = a; }
    float rt;
    if (adf > ab)      { float q = ab / adf; rt = adf * sqrtf(1.f + q * q); }
    else if (adf < ab) { float q = adf / ab; rt = ab * sqrtf(1.f + q * q); }
    else               rt = ab * sqrtf(2.f);
    int sgn1;
    if (sm < 0.f)      { rt1 = 0.5f * (sm - rt); sgn1 = -1; rt2 = (acmx / rt1) * acmn - (b / rt1) * b; }
    else if (sm > 0.f) { rt1 = 0.5f * (sm + rt); sgn1 =  1; rt2 = (acmx / rt1) * acmn - (b / rt1) * b; }
    else               { rt1 = 0.5f * rt; rt2 = -0.5f * rt; sgn1 = 1; }
    float cs; int sgn2;
    if (df >= 0.f) { cs = df + rt; sgn2 = 1; } else { cs = df - rt; sgn2 = -1; }
    float acs = fabsf(cs);
    if (acs > ab) { float ct = -tb / cs; sn1 = 1.f / sqrtf(1.f + ct * ct); cs1 = ct * sn1; }
    else {
        if (ab == 0.f) { cs1 = 1.f; sn1 = 0.f; }
        else { float tn = -cs / tb; cs1 = 1.f / sqrtf(1.f + tn * tn); sn1 = tn * cs1; }
    }
    if (sgn1 == sgn2) { float tn = cs1; cs1 = -sn1; sn1 = tn; }
}

// ---------------------------------------------------------------- K3
// one 64-lane wave per batch matrix; scalar logic replicated on all lanes
// (identical data -> uniform branches), O(n^2) parts lane-parallel.
__global__ __launch_bounds__(64) void eigh_feat_kernel(
    const float* __restrict__ G, const float* __restrict__ ema,
    float* __restrict__ out)
{
#pragma clang fp contract(off)
    const int b = blockIdx.x;
    const int lane = threadIdx.x;
    const int n = N24;

    __shared__ float A[N24 * N24];    // col-major A[i + 24*j]
    __shared__ float Zl[N24 * N24];   // col-major, column j = eigenvector j
    __shared__ float d[N24 + 1], e[N24 + 1], tau[N24 + 1], wc[N24 + 1], wsn[N24 + 1];
    __shared__ float hv[N24], hw[N24];
    __shared__ float Sarr[N24], snorm[N24];

    for (int idx = lane; idx < n * n; idx += 64) A[idx] = G[(size_t)b * n * n + idx];
    __syncthreads();

    // ---------- ssytd2 (lower) ----------
    for (int i = 0; i < n - 1; ++i) {
        const int mlen = n - 1 - i;
        float alpha = A[(i + 1) + N24 * i];
        float ss = 0.f;
        for (int r = i + 2; r < n; ++r) { float t = A[r + N24 * i]; ss += t * t; }
        float xnorm = sqrtf(ss);
        if (xnorm == 0.f) {
            tau[i + 1] = 0.f;
            e[i + 1] = alpha;
            d[i + 1] = A[i + N24 * i];
            __syncthreads();
            continue;
        }
        float beta = -copysignf(lapy2f(alpha, xnorm), alpha);
        float taui = (beta - alpha) / beta;
        float scal = 1.f / (alpha - beta);
        tau[i + 1] = taui;
        e[i + 1] = beta;
        __syncthreads();
        if (lane >= i + 2 && lane < n) A[lane + N24 * i] *= scal;
        __syncthreads();
        if (lane < mlen) hv[lane] = (lane == 0) ? 1.f : A[(i + 1 + lane) + N24 * i];
        __syncthreads();
        if (lane < mlen) {                      // x = tau * Asub * v  (symmetric, lower)
            float acc = 0.f;
            int gr = i + 1 + lane;
            for (int c2 = 0; c2 < mlen; ++c2) {
                int gc = i + 1 + c2;
                float av = (gr >= gc) ? A[gr + N24 * gc] : A[gc + N24 * gr];
                acc += av * hv[c2];
            }
            hw[lane] = taui * acc;
        }
        __syncthreads();
        float dot = 0.f;                        // redundant on all lanes
        for (int r2 = 0; r2 < mlen; ++r2) dot += hw[r2] * hv[r2];
        float alpha2 = -0.5f * taui * dot;
        __syncthreads();
        if (lane < mlen) hw[lane] += alpha2 * hv[lane];
        __syncthreads();
        if (lane < mlen) {                      // rank-2 update, lower triangle
            for (int c2 = 0; c2 <= lane; ++c2)
                A[(i + 1 + lane) + N24 * (i + 1 + c2)] -= hv[lane] * hw[c2] + hw[lane] * hv[c2];
        }
        __syncthreads();
        d[i + 1] = A[i + N24 * i];
    }
    d[n] = A[(n - 1) + N24 * (n - 1)];
    __syncthreads();

    // ---------- ssteqr('I') ----------
    for (int idx = lane; idx < n * n; idx += 64) Zl[idx] = 0.f;
    __syncthreads();
    if (lane < n) Zl[lane + N24 * lane] = 1.f;
    __syncthreads();

    {
        const float eps_    = 0x1p-24f;
        const float eps2_   = 0x1p-48f;
        const float safmin_ = 0x1p-126f;
        const float ssfmax_ = 3.0744573e+18f;  // sqrt(1/safmin)/3
        const float ssfmin_ = 0x1p-15f;        // sqrt(safmin)/eps^2
        const int nmaxit = n * 30;
        int jtot = 0, l1 = 1;
        int l = 0, lsv = 0, lend = 0, lendsv = 0, mb = 0, iscale = 0;
        float anorm = 0.f, p = 0.f, g = 0.f, r_ = 0.f, c_ = 0.f, s_ = 0.f, f_ = 0.f, b_ = 0.f;
        float rt1 = 0.f, rt2 = 0.f, cc = 0.f, sn = 0.f;
        int m_ = 0, i_ = 0, j_ = 0, fnd = 0;

L10:
        if (l1 > n) goto L160;
        if (l1 > 1) e[l1 - 1] = 0.f;
        fnd = 0;
        if (l1 <= n - 1) {
            for (m_ = l1; m_ <= n - 1; ++m_) {
                float tst = fabsf(e[m_]);
                if (tst == 0.f) { fnd = 1; break; }
                if (tst <= (sqrtf(fabsf(d[m_])) * sqrtf(fabsf(d[m_ + 1]))) * eps_) {
                    e[m_] = 0.f; fnd = 1; break;
                }
            }
        }
        if (!fnd) m_ = n;
        l = l1; lsv = l; lend = m_; lendsv = lend; l1 = m_ + 1;
        if (lend == l) goto L10;

        anorm = 0.f;
        for (j_ = l; j_ <= lend; ++j_) anorm = fmaxf(anorm, fabsf(d[j_]));
        for (j_ = l; j_ <= lend - 1; ++j_) anorm = fmaxf(anorm, fabsf(e[j_]));
        iscale = 0;
        if (anorm == 0.f) goto L10;
        if (anorm > ssfmax_) {
            iscale = 1;
            { float mul = ssfmax_ / anorm;
              for (j_ = l; j_ <= lend; ++j_) d[j_] *= mul;
              for (j_ = l; j_ <= lend - 1; ++j_) e[j_] *= mul; }
        } else if (anorm < ssfmin_) {
            iscale = 2;
            { float mul = ssfmin_ / anorm;
              for (j_ = l; j_ <= lend; ++j_) d[j_] *= mul;
              for (j_ = l; j_ <= lend - 1; ++j_) e[j_] *= mul; }
        }
        if (fabsf(d[lend]) < fabsf(d[l])) { lend = lsv; l = lendsv; }

        if (lend > l) {
            // ------------- QL -------------
L40:
            if (l != lend) {
                fnd = 0;
                for (m_ = l; m_ <= lend - 1; ++m_) {
                    float tst = e[m_] * e[m_];
                    if (tst <= (eps2_ * fabsf(d[m_])) * fabsf(d[m_ + 1]) + safmin_) { fnd = 1; break; }
                }
                if (!fnd) m_ = lend;
            } else m_ = lend;
            if (m_ < lend) e[m_] = 0.f;
            mb = m_;
            p = d[l];
            if (mb == l) goto L80;
            if (mb == l + 1) {                      // 2x2
                slaev2_(d[l], e[l], d[l + 1], rt1, rt2, cc, sn);
                __syncthreads();
                if (lane < n) {                     // cols 1-based (l,l+1) -> 0-based (l-1,l)
                    float t = Zl[lane + N24 * l];
                    Zl[lane + N24 * l]       = cc * t - sn * Zl[lane + N24 * (l - 1)];
                    Zl[lane + N24 * (l - 1)] = sn * t + cc * Zl[lane + N24 * (l - 1)];
                }
                __syncthreads();
                d[l] = rt1; d[l + 1] = rt2; e[l] = 0.f;
                l = l + 2;
                if (l <= lend) goto L40;
                goto L140;
            }
            if (jtot == nmaxit) goto L140;
            jtot = jtot + 1;
            g = (d[l + 1] - p) / (2.f * e[l]);
            r_ = lapy2f(g, 1.f);
            g = d[mb] - p + (e[l] / (g + copysignf(r_, g)));
            s_ = 1.f; c_ = 1.f; p = 0.f;
            for (i_ = mb - 1; i_ >= l; --i_) {
                f_ = s_ * e[i_];
                b_ = c_ * e[i_];
                slartg_(g, f_, c_, s_, r_);
                if (i_ != mb - 1) e[i_ + 1] = r_;
                g = d[i_ + 1] - p;
                r_ = (d[i_] - g) * s_ + 2.f * c_ * b_;
                p = s_ * r_;
                d[i_ + 1] = g + p;
                g = c_ * r_ - b_;
                wc[i_] = c_;
                wsn[i_] = -s_;
            }
            __syncthreads();
            if (lane < n) {                         // dlasr 'R','V','B'
                for (j_ = mb - 1; j_ >= l; --j_) {
                    float cj = wc[j_], sj = wsn[j_];
                    float t = Zl[lane + N24 * j_];
                    Zl[lane + N24 * j_]       = cj * t - sj * Zl[lane + N24 * (j_ - 1)];
                    Zl[lane + N24 * (j_ - 1)] = sj * t + cj * Zl[lane + N24 * (j_ - 1)];
                }
            }
            __syncthreads();
            d[l] = d[l] - p;
            e[l] = g;
            goto L40;
L80:
            d[l] = p;
            l = l + 1;
            if (l <= lend) goto L40;
            goto L140;
        } else {
            // ------------- QR -------------
L90:
            if (l != lend) {
                fnd = 0;
                for (m_ = l; m_ >= lend + 1; --m_) {
                    float tst = e[m_ - 1] * e[m_ - 1];
                    if (tst <= (eps2_ * fabsf(d[m_])) * fabsf(d[m_ - 1]) + safmin_) { fnd = 1; break; }
                }
                if (!fnd) m_ = lend;
            } else m_ = lend;
            if (m_ > lend) e[m_ - 1] = 0.f;
            mb = m_;
            p = d[l];
            if (mb == l) goto L130;
            if (mb == l - 1) {                      // 2x2
                slaev2_(d[l - 1], e[l - 1], d[l], rt1, rt2, cc, sn);
                __syncthreads();
                if (lane < n) {                     // cols 1-based (l-1,l) -> 0-based (l-2,l-1)
                    float t = Zl[lane + N24 * (l - 1)];
                    Zl[lane + N24 * (l - 1)] = cc * t - sn * Zl[lane + N24 * (l - 2)];
                    Zl[lane + N24 * (l - 2)] = sn * t + cc * Zl[lane + N24 * (l - 2)];
                }
                __syncthreads();
                d[l - 1] = rt1; d[l] = rt2; e[l - 1] = 0.f;
                l = l - 2;
                if (l >= lend) goto L90;
                goto L140;
            }
            if (jtot == nmaxit) goto L140;
            jtot = jtot + 1;
            g = (d[l - 1] - p) / (2.f * e[l - 1]);
            r_ = lapy2f(g, 1.f);
            g = d[mb] - p + (e[l - 1] / (g + copysignf(r_, g)));
            s_ = 1.f; c_ = 1.f; p = 0.f;
            for (i_ = mb; i_ <= l - 1; ++i_) {
                f_ = s_ * e[i_];
                b_ = c_ * e[i_];
                slartg_(g, f_, c_, s_, r_);
                if (i_ != mb) e[i_ - 1] = r_;
                g = d[i_] - p;
                r_ = (d[i_ + 1] - g) * s_ + 2.f * c_ * b_;
                p = s_ * r_;
                d[i_] = g + p;
                g = c_ * r_ - b_;
                wc[i_] = c_;
                wsn[i_] = s_;
            }
            __syncthreads();
            if (lane < n) {                         // dlasr 'R','V','F'
                for (j_ = mb; j_ <= l - 1; ++j_) {
                    float cj = wc[j_], sj = wsn[j_];
                    float t = Zl[lane + N24 * j_];
                    Zl[lane + N24 * j_]       = cj * t - sj * Zl[lane + N24 * (j_ - 1)];
                    Zl[lane + N24 * (j_ - 1)] = sj * t + cj * Zl[lane + N24 * (j_ - 1)];
                }
            }
            __syncthreads();
            d[l] = d[l] - p;
            e[l - 1] = g;
            goto L90;
L130:
            d[l] = p;
            l = l - 1;
            if (l >= lend) goto L90;
            goto L140;
        }
L140:
        if (iscale == 1) {
            float mul = anorm / ssfmax_;
            for (j_ = lsv; j_ <= lendsv; ++j_) d[j_] *= mul;
            for (j_ = lsv; j_ <= lendsv - 1; ++j_) e[j_] *= mul;
        } else if (iscale == 2) {
            float mul = anorm / ssfmin_;
            for (j_ = lsv; j_ <= lendsv; ++j_) d[j_] *= mul;
            for (j_ = lsv; j_ <= lendsv - 1; ++j_) e[j_] *= mul;
        }
        if (jtot < nmaxit) goto L10;
        goto L160;

L160:
        // selection sort ascending, swapping Z columns (matches dsteqr)
        for (int ii = 2; ii <= n; ++ii) {
            int ia = ii - 1, ka = ia;
            float pp = d[ia];
            for (int jj = ii; jj <= n; ++jj)
                if (d[jj] < pp) { ka = jj; pp = d[jj]; }
            if (ka != ia) {
                d[ka] = d[ia];
                d[ia] = pp;
                __syncthreads();
                if (lane < n) {
                    float t = Zl[lane + N24 * (ia - 1)];
                    Zl[lane + N24 * (ia - 1)] = Zl[lane + N24 * (ka - 1)];
                    Zl[lane + N24 * (ka - 1)] = t;
                }
                __syncthreads();
            }
        }
    }

    // ---------- sormtr: Z := H(1)...H(n-1) * Z  (apply i = n-2..0, lane = column) ----------
    __syncthreads();
    for (int i = n - 2; i >= 0; --i) {
        float taui = tau[i + 1];
        if (taui != 0.f && lane < n) {
            int j = lane;
            float w_ = Zl[(i + 1) + N24 * j];
            for (int r = i + 2; r < n; ++r) w_ += A[r + N24 * i] * Zl[r + N24 * j];
            Zl[(i + 1) + N24 * j] -= taui * w_;
            for (int r = i + 2; r < n; ++r) Zl[r + N24 * j] -= taui * (A[r + N24 * i] * w_);
        }
    }
    __syncthreads();

    // ---------- S, Vh, features, novelty ----------
    const int S_OFF = 0, VH_OFF = 1536, F_OFF = 38400, NOV_OFF = 41600;
    if (lane < n) {
        float ev = d[n - lane];                    // descending
        float s0 = sqrtf(fmaxf(ev, 0.f));
        s0 = fmaxf(s0, 1e-6f);
        if (!isfinite(s0)) s0 = 1.f;
        Sarr[lane] = s0;
    }
    __syncthreads();
    if (lane < n) {
        out[S_OFF + b * 24 + lane] = Sarr[lane];
        out[NOV_OFF + b * 24 + lane] = Sarr[lane] - ema[lane];
    }
    for (int idx = lane; idx < 576; idx += 64) {   // Vh[j][i] = Z[i][23-j]
        int j = idx / 24, i2 = idx % 24;
        float vv = Zl[i2 + N24 * (23 - j)];
        if (!isfinite(vv)) vv = 0.f;
        out[VH_OFF + b * 576 + idx] = vv;
    }
    float sum_ = 0.f;
    for (int j2 = 0; j2 < n; ++j2) sum_ += Sarr[j2];
    float denom = sum_ + 1e-8f;
    if (lane < n) snorm[lane] = Sarr[lane] / denom;
    __syncthreads();
    float ent = 0.f;
    for (int j2 = 0; j2 < n; ++j2) {
        float sn2 = snorm[j2];
        ent -= sn2 * logf(fmaxf(sn2, 1e-8f));
    }
    float sumsq = 0.f, diagsq = 0.f;
    for (int idx = 0; idx < 576; ++idx) { float z = Zl[idx]; sumsq += z * z; }
    for (int j2 = 0; j2 < n; ++j2) { float dv = Zl[j2 + N24 * (23 - j2)]; diagsq += dv * dv; }
    float offd = fmaxf(sumsq - diagsq, 0.f);
    if (lane < n) {
        float v0 = snorm[lane]; if (!isfinite(v0)) v0 = 0.f;
        out[F_OFF + b * 50 + lane] = v0;
        float dv = Zl[lane + N24 * (23 - lane)]; if (!isfinite(dv)) dv = 0.f;
        out[F_OFF + b * 50 + 24 + lane] = dv;
    }
    if (lane == 0) {
        if (!isfinite(offd)) offd = 0.f;
        if (!isfinite(ent)) ent = 0.f;
        out[F_OFF + b * 50 + 48] = offd;
        out[F_OFF + b * 50 + 49] = ent;
    }
}

// ---------------------------------------------------------------- launch
extern "C" void kernel_launch(void* const* d_in, const int* in_sizes, int n_in,
                              void* d_out, int out_size, void* d_ws, size_t ws_size,
                              hipStream_t stream)
{
    const float* x   = (const float*)d_in[0];
    const float* w   = (const float*)d_in[1];
    const float* ema = (const float*)d_in[2];
    float* out = (float*)d_out;

    // ws layout: partial (1024*300 f64 = 2.4576 MB) | G (64*576 f32 = 147 KB)
    double* partial = (double*)d_ws;
    float* G = (float*)((char*)d_ws + (size_t)1024 * 300 * sizeof(double));

    hipLaunchKernelGGL(proj_gram_kernel, dim3(1024), dim3(256), 0, stream, x, w, partial);
    hipLaunchKernelGGL(gram_reduce_kernel, dim3(64), dim3(320), 0, stream, partial, G);
    hipLaunchKernelGGL(eigh_feat_kernel, dim3(64), dim3(64), 0, stream, G, ema, out);
}

// Round 2
// 589.993 us; speedup vs baseline: 1.1156x; 1.1156x over previous
//
#include <hip/hip_runtime.h>
#include <math.h>

// SVDObserver: x (64,512,64,64) f32, w_proj (24,512) f32, ema_s (24) f32
// outputs (flat f32 concat): S (64,24) | Vh (64,24,24) | features (64,50) | novelty (64,24)
//
//  K1 proj_gram: h[b,n,:] = W x[b,:,n]; 4 pixels/thread (float4), per-256-pixel
//     fp64 Gram partials in EXACT same order/layout as the passing r1 kernel.
//  K2 gram_reduce: sum 16 partials -> G (64,24,24) fp32.  (unchanged)
//  K3 eigh_feat: LAPACK ssyevd path (ssytd2 -> ssteqr -> sormtr), arithmetic
//     ORDER IDENTICAL to r1 (bit-exact), but ssteqr scalar state now lives in
//     lane-distributed registers (v_readlane broadcast) instead of LDS, and Z
//     rotations use a register carry + stride-25 Zl (bank-conflict-free).

#define N24 24
#define ZS 25   // Zl row stride (odd -> conflict-free)

// ---------------------------------------------------------------- K1
__global__ __launch_bounds__(256) void proj_gram_kernel(
    const float* __restrict__ x, const float* __restrict__ w,
    double* __restrict__ partial)
{
    const int b   = blockIdx.x >> 2;
    const int q   = blockIdx.x & 3;
    const int tid = threadIdx.x;
    const int n0  = (q << 10) | (tid << 2);       // pixel base (4 consecutive)
    __shared__ __align__(16) float smem[24 * 512]; // 48 KB (wl, reused as hl)
    float* wl = smem;
    for (int i2 = tid; i2 < 24 * 512; i2 += 256) wl[i2] = w[i2];
    __syncthreads();

    const float* xb = x + ((size_t)b << 21) + n0; // b*512*4096 + n0
    float h[4][24];
#pragma unroll
    for (int j = 0; j < 4; ++j)
#pragma unroll
        for (int k = 0; k < 24; ++k) h[j][k] = 0.f;

#pragma unroll 2
    for (int c = 0; c < 512; c += 4) {
        const float4 a0 = *reinterpret_cast<const float4*>(xb + ((size_t)(c + 0) << 12));
        const float4 a1 = *reinterpret_cast<const float4*>(xb + ((size_t)(c + 1) << 12));
        const float4 a2 = *reinterpret_cast<const float4*>(xb + ((size_t)(c + 2) << 12));
        const float4 a3 = *reinterpret_cast<const float4*>(xb + ((size_t)(c + 3) << 12));
#pragma unroll
        for (int k = 0; k < 24; ++k) {
            const float4 wv = *reinterpret_cast<const float4*>(&wl[k * 512 + c]);
            h[0][k] += wv.x * a0.x + wv.y * a1.x + wv.z * a2.x + wv.w * a3.x;
            h[1][k] += wv.x * a0.y + wv.y * a1.y + wv.z * a2.y + wv.w * a3.y;
            h[2][k] += wv.x * a0.z + wv.y * a1.z + wv.z * a2.z + wv.w * a3.z;
            h[3][k] += wv.x * a0.w + wv.y * a1.w + wv.z * a2.w + wv.w * a3.w;
        }
    }
    __syncthreads();           // everyone done reading wl

    float* hl = smem;          // reuse: 256 px * 24 floats = 24 KB
    const int s_own = tid >> 6, l64 = tid & 63;
    for (int s2 = 0; s2 < 4; ++s2) {
        if (s_own == s2) {
#pragma unroll
            for (int j = 0; j < 4; ++j)
#pragma unroll
                for (int k = 0; k < 24; ++k)
                    hl[((l64 << 2) + j) * 24 + k] = h[j][k];
        }
        __syncthreads();
        // 300 unique pairs (k<=m), fp64 accumulation over 256 pixels, i2 order 0..255
        for (int p = tid; p < 300; p += 256) {
            int k = 0, pp = p;
            while (pp >= 24 - k) { pp -= 24 - k; ++k; }
            int m = k + pp;
            double acc = 0.0;
            for (int i2 = 0; i2 < 256; ++i2)
                acc += (double)hl[i2 * 24 + k] * (double)hl[i2 * 24 + m];
            partial[((size_t)(b * 16 + (q << 2) + s2)) * 300 + p] = acc;
        }
        __syncthreads();
    }
}

// ---------------------------------------------------------------- K2
__global__ __launch_bounds__(320) void gram_reduce_kernel(
    const double* __restrict__ partial, float* __restrict__ G)
{
    const int b = blockIdx.x;
    const int p = threadIdx.x;
    if (p >= 300) return;
    int k = 0, pp = p;
    while (pp >= 24 - k) { pp -= 24 - k; ++k; }
    int m = k + pp;
    double acc = 0.0;
    for (int t = 0; t < 16; ++t)
        acc += partial[((size_t)(b * 16 + t)) * 300 + p];
    float v = (float)acc;
    G[b * 576 + k * 24 + m] = v;
    G[b * 576 + m * 24 + k] = v;   // exactly symmetric
}

// ------------------------------------------------------- LAPACK helpers
__device__ __forceinline__ float rlf(float v, int l) {
    return __int_as_float(__builtin_amdgcn_readlane(__float_as_int(v), l));
}

__device__ __forceinline__ float lapy2f(float xx, float yy) {
#pragma clang fp contract(off)
    float xa = fabsf(xx), ya = fabsf(yy);
    float w = fmaxf(xa, ya), z = fminf(xa, ya);
    if (z == 0.f) return w;
    float q = z / w;
    return w * sqrtf(1.f + q * q);
}

__device__ __forceinline__ void slartg_(float f, float g, float& c, float& s, float& r) {
#pragma clang fp contract(off)
    if (g == 0.f) { c = 1.f; s = 0.f; r = f; }
    else if (f == 0.f) { c = 0.f; s = copysignf(1.f, g); r = fabsf(g); }
    else {
        float f1 = fabsf(f), g1 = fabsf(g);
        const float rtmin_ = 0x1p-63f;          // sqrt(safmin)
        const float rtmax_ = 1.8446743e+19f;    // ~sqrt(safmax)
        float d, p;
        if (f1 > rtmin_ && f1 < rtmax_ && g1 > rtmin_ && g1 < rtmax_) {
            d = sqrtf(f * f + g * g);
            p = 1.f / d;
            c = f1 * p;
            s = g * copysignf(p, f);
            r = copysignf(d, f);
        } else {
            float u = fminf(3.4028235e+38f, fmaxf(0x1p-126f, fmaxf(f1, g1)));
            float fs = f / u, gs = g / u;
            d = sqrtf(fs * fs + gs * gs);
            p = 1.f / d;
            c = fabsf(fs) * p;
            s = gs * copysignf(p, f);
            r = copysignf(d, f) * u;
        }
    }
}

__device__ __forceinline__ void slaev2_(float a, float b, float cc,
                                        float& rt1, float& rt2, float& cs1, float& sn1) {
#pragma clang fp contract(off)
    float sm = a + cc, df = a - cc, adf = fabsf(df);
    float tb = b + b, ab = fabsf(tb);
    float acmx, acmn;
    if (fabsf(a) > fabsf(cc)) { acmx = a; acmn = cc; } else { acmx = cc; acmn = a; }
    float rt;
    if (adf > ab)      { float q = ab / adf; rt = adf * sqrtf(1.f + q * q); }
    else if (adf < ab) { float q = adf / ab; rt = ab * sqrtf(1.f + q * q); }
    else               rt = ab * sqrtf(2.f);
    int sgn1;
    if (sm < 0.f)      { rt1 = 0.5f * (sm - rt); sgn1 = -1; rt2 = (acmx / rt1) * acmn - (b / rt1) * b; }
    else if (sm > 0.f) { rt1 = 0.5f * (sm + rt); sgn1 =  1; rt2 = (acmx / rt1) * acmn - (b / rt1) * b; }
    else               { rt1 = 0.5f * rt; rt2 = -0.5f * rt; sgn1 = 1; }
    float cs; int sgn2;
    if (df >= 0.f) { cs = df + rt; sgn2 = 1; } else { cs = df - rt; sgn2 = -1; }
    float acs = fabsf(cs);
    if (acs > ab) { float ct = -tb / cs; sn1 = 1.f / sqrtf(1.f + ct * ct); cs1 = ct * sn1; }
    else {
        if (ab == 0.f) { cs1 = 1.f; sn1 = 0.f; }
        else { float tn = -cs / tb; cs1 = 1.f / sqrtf(1.f + tn * tn); sn1 = tn * cs1; }
    }
    if (sgn1 == sgn2) { float tn = cs1; cs1 = -sn1; sn1 = tn; }
}

// d/e register accessors (1-based index j, owner lane j-1); values are
// uniform across lanes, readlane ignores EXEC.
#define RD(j)   rlf(dr, (j) - 1)
#define RE(j)   rlf(er, (j) - 1)
#define WD(j,v) { float _v = (v); int _j = (j) - 1; if (lane == _j) dr = _v; }
#define WE(j,v) { float _v = (v); int _j = (j) - 1; if (lane == _j) er = _v; }

// ---------------------------------------------------------------- K3
// one 64-lane wave per batch matrix; uniform control flow; ssteqr scalar
// state in lane-distributed registers (bit-identical arithmetic to r1).
__global__ __launch_bounds__(64) void eigh_feat_kernel(
    const float* __restrict__ G, const float* __restrict__ ema,
    float* __restrict__ out)
{
#pragma clang fp contract(off)
    const int b = blockIdx.x;
    const int lane = threadIdx.x;
    const int n = N24;

    __shared__ float A[N24 * N24];      // col-major A[i + 24*j]
    __shared__ float Zl[N24 * ZS];      // row i, col j at Zl[i + ZS*j]
    __shared__ float dl[N24 + 1], el[N24 + 1], tau[N24 + 1];
    __shared__ float hv[N24], hw[N24];
    __shared__ float Sarr[N24], snorm[N24];

    for (int idx = lane; idx < n * n; idx += 64) A[idx] = G[(size_t)b * n * n + idx];
    __syncthreads();

    // ---------- ssytd2 (lower) ---------- (unchanged arithmetic)
    for (int i = 0; i < n - 1; ++i) {
        const int mlen = n - 1 - i;
        float alpha = A[(i + 1) + N24 * i];
        float ss = 0.f;
        for (int r = i + 2; r < n; ++r) { float t = A[r + N24 * i]; ss += t * t; }
        float xnorm = sqrtf(ss);
        if (xnorm == 0.f) {
            if (lane == 0) { tau[i + 1] = 0.f; el[i + 1] = alpha; dl[i + 1] = A[i + N24 * i]; }
            __syncthreads();
            continue;
        }
        float beta = -copysignf(lapy2f(alpha, xnorm), alpha);
        float taui = (beta - alpha) / beta;
        float scal = 1.f / (alpha - beta);
        if (lane == 0) { tau[i + 1] = taui; el[i + 1] = beta; }
        __syncthreads();
        if (lane >= i + 2 && lane < n) A[lane + N24 * i] *= scal;
        __syncthreads();
        if (lane < mlen) hv[lane] = (lane == 0) ? 1.f : A[(i + 1 + lane) + N24 * i];
        __syncthreads();
        if (lane < mlen) {                      // x = tau * Asub * v  (symmetric, lower)
            float acc = 0.f;
            int gr = i + 1 + lane;
            for (int c2 = 0; c2 < mlen; ++c2) {
                int gc = i + 1 + c2;
                float av = (gr >= gc) ? A[gr + N24 * gc] : A[gc + N24 * gr];
                acc += av * hv[c2];
            }
            hw[lane] = taui * acc;
        }
        __syncthreads();
        float dot = 0.f;                        // redundant on all lanes
        for (int r2 = 0; r2 < mlen; ++r2) dot += hw[r2] * hv[r2];
        float alpha2 = -0.5f * taui * dot;
        __syncthreads();
        if (lane < mlen) hw[lane] += alpha2 * hv[lane];
        __syncthreads();
        if (lane < mlen) {                      // rank-2 update, lower triangle
            for (int c2 = 0; c2 <= lane; ++c2)
                A[(i + 1 + lane) + N24 * (i + 1 + c2)] -= hv[lane] * hw[c2] + hw[lane] * hv[c2];
        }
        __syncthreads();
        if (lane == 0) dl[i + 1] = A[i + N24 * i];
        __syncthreads();
    }
    if (lane == 0) dl[n] = A[(n - 1) + N24 * (n - 1)];
    __syncthreads();

    // ---------- ssteqr('I'), state in registers ----------
    for (int idx = lane; idx < N24 * ZS; idx += 64) Zl[idx] = 0.f;
    __syncthreads();
    if (lane < n) Zl[lane + ZS * lane] = 1.f;
    __syncthreads();

    float dr = (lane < 24) ? dl[lane + 1] : 0.f;   // lane i holds d[i+1]
    float er = (lane < 23) ? el[lane + 1] : 0.f;   // lane i holds e[i+1]
    float wcr = 0.f, wsr = 0.f;                    // lane i holds rot c/s for index i+1

    {
        const float eps_    = 0x1p-24f;
        const float eps2_   = 0x1p-48f;
        const float safmin_ = 0x1p-126f;
        const float ssfmax_ = 3.0744573e+18f;  // sqrt(1/safmin)/3
        const float ssfmin_ = 0x1p-15f;        // sqrt(safmin)/eps^2
        const int nmaxit = n * 30;
        int jtot = 0, l1 = 1;
        int l = 0, lsv = 0, lend = 0, lendsv = 0, mb = 0, iscale = 0;
        float anorm = 0.f, p = 0.f, g = 0.f, r_ = 0.f, c_ = 0.f, s_ = 0.f, f_ = 0.f, b_ = 0.f;
        float rt1 = 0.f, rt2 = 0.f, cc = 0.f, sn = 0.f;
        int m_ = 0, i_ = 0, j_ = 0, fnd = 0;

L10:
        if (l1 > n) goto L160;
        if (l1 > 1) WE(l1 - 1, 0.f);
        fnd = 0;
        if (l1 <= n - 1) {
            for (m_ = l1; m_ <= n - 1; ++m_) {
                float tst = fabsf(RE(m_));
                if (tst == 0.f) { fnd = 1; break; }
                if (tst <= (sqrtf(fabsf(RD(m_))) * sqrtf(fabsf(RD(m_ + 1)))) * eps_) {
                    WE(m_, 0.f); fnd = 1; break;
                }
            }
        }
        if (!fnd) m_ = n;
        l = l1; lsv = l; lend = m_; lendsv = lend; l1 = m_ + 1;
        if (lend == l) goto L10;

        anorm = 0.f;
        for (j_ = l; j_ <= lend; ++j_) anorm = fmaxf(anorm, fabsf(RD(j_)));
        for (j_ = l; j_ <= lend - 1; ++j_) anorm = fmaxf(anorm, fabsf(RE(j_)));
        iscale = 0;
        if (anorm == 0.f) goto L10;
        if (anorm > ssfmax_) {
            iscale = 1;
            float mul = ssfmax_ / anorm;
            if (lane + 1 >= l && lane + 1 <= lend) dr *= mul;
            if (lane + 1 >= l && lane + 1 <= lend - 1) er *= mul;
        } else if (anorm < ssfmin_) {
            iscale = 2;
            float mul = ssfmin_ / anorm;
            if (lane + 1 >= l && lane + 1 <= lend) dr *= mul;
            if (lane + 1 >= l && lane + 1 <= lend - 1) er *= mul;
        }
        if (fabsf(RD(lend)) < fabsf(RD(l))) { lend = lsv; l = lendsv; }

        if (lend > l) {
            // ------------- QL -------------
L40:
            if (l != lend) {
                fnd = 0;
                for (m_ = l; m_ <= lend - 1; ++m_) {
                    float em = RE(m_);
                    float tst = em * em;
                    if (tst <= (eps2_ * fabsf(RD(m_))) * fabsf(RD(m_ + 1)) + safmin_) { fnd = 1; break; }
                }
                if (!fnd) m_ = lend;
            } else m_ = lend;
            if (m_ < lend) WE(m_, 0.f);
            mb = m_;
            p = RD(l);
            if (mb == l) goto L80;
            if (mb == l + 1) {                      // 2x2
                slaev2_(RD(l), RE(l), RD(l + 1), rt1, rt2, cc, sn);
                if (lane < n) {
                    float z1 = Zl[lane + ZS * l];
                    float z0 = Zl[lane + ZS * (l - 1)];
                    Zl[lane + ZS * l]       = cc * z1 - sn * z0;
                    Zl[lane + ZS * (l - 1)] = sn * z1 + cc * z0;
                }
                WD(l, rt1); WD(l + 1, rt2); WE(l, 0.f);
                l = l + 2;
                if (l <= lend) goto L40;
                goto L140;
            }
            if (jtot == nmaxit) goto L140;
            jtot = jtot + 1;
            g = (RD(l + 1) - p) / (2.f * RE(l));
            r_ = lapy2f(g, 1.f);
            g = RD(mb) - p + (RE(l) / (g + copysignf(r_, g)));
            s_ = 1.f; c_ = 1.f; p = 0.f;
            for (i_ = mb - 1; i_ >= l; --i_) {
                float ei = RE(i_);
                f_ = s_ * ei;
                b_ = c_ * ei;
                slartg_(g, f_, c_, s_, r_);
                if (i_ != mb - 1) WE(i_ + 1, r_);
                g = RD(i_ + 1) - p;
                r_ = (RD(i_) - g) * s_ + 2.f * c_ * b_;
                p = s_ * r_;
                WD(i_ + 1, g + p);
                g = c_ * r_ - b_;
                if (lane == i_ - 1) { wcr = c_; wsr = -s_; }
            }
            if (lane < n) {                         // dlasr 'R','V','B' (register carry)
                float carry = Zl[lane + ZS * (mb - 1)];
                for (j_ = mb - 1; j_ >= l; --j_) {
                    float cj = rlf(wcr, j_ - 1), sj = rlf(wsr, j_ - 1);
                    float prev = Zl[lane + ZS * (j_ - 1)];
                    Zl[lane + ZS * j_] = cj * carry - sj * prev;
                    carry = sj * carry + cj * prev;
                }
                Zl[lane + ZS * (l - 1)] = carry;
            }
            WD(l, RD(l) - p);
            WE(l, g);
            goto L40;
L80:
            WD(l, p);
            l = l + 1;
            if (l <= lend) goto L40;
            goto L140;
        } else {
            // ------------- QR -------------
L90:
            if (l != lend) {
                fnd = 0;
                for (m_ = l; m_ >= lend + 1; --m_) {
                    float em = RE(m_ - 1);
                    float tst = em * em;
                    if (tst <= (eps2_ * fabsf(RD(m_))) * fabsf(RD(m_ - 1)) + safmin_) { fnd = 1; break; }
                }
                if (!fnd) m_ = lend;
            } else m_ = lend;
            if (m_ > lend) WE(m_ - 1, 0.f);
            mb = m_;
            p = RD(l);
            if (mb == l) goto L130;
            if (mb == l - 1) {                      // 2x2
                slaev2_(RD(l - 1), RE(l - 1), RD(l), rt1, rt2, cc, sn);
                if (lane < n) {
                    float z1 = Zl[lane + ZS * (l - 1)];
                    float z0 = Zl[lane + ZS * (l - 2)];
                    Zl[lane + ZS * (l - 1)] = cc * z1 - sn * z0;
                    Zl[lane + ZS * (l - 2)] = sn * z1 + cc * z0;
                }
                WD(l - 1, rt1); WD(l, rt2); WE(l - 1, 0.f);
                l = l - 2;
                if (l >= lend) goto L90;
                goto L140;
            }
            if (jtot == nmaxit) goto L140;
            jtot = jtot + 1;
            g = (RD(l - 1) - p) / (2.f * RE(l - 1));
            r_ = lapy2f(g, 1.f);
            g = RD(mb) - p + (RE(l - 1) / (g + copysignf(r_, g)));
            s_ = 1.f; c_ = 1.f; p = 0.f;
            for (i_ = mb; i_ <= l - 1; ++i_) {
                float ei = RE(i_);
                f_ = s_ * ei;
                b_ = c_ * ei;
                slartg_(g, f_, c_, s_, r_);
                if (i_ != mb) WE(i_ - 1, r_);
                g = RD(i_) - p;
                r_ = (RD(i_ + 1) - g) * s_ + 2.f * c_ * b_;
                p = s_ * r_;
                WD(i_, g + p);
                g = c_ * r_ - b_;
                if (lane == i_ - 1) { wcr = c_; wsr = s_; }
            }
            if (lane < n) {                         // dlasr 'R','V','F' (register carry)
                float carryPrev = Zl[lane + ZS * (mb - 1)];
                for (j_ = mb; j_ <= l - 1; ++j_) {
                    float cj = rlf(wcr, j_ - 1), sj = rlf(wsr, j_ - 1);
                    float t = Zl[lane + ZS * j_];
                    Zl[lane + ZS * (j_ - 1)] = sj * t + cj * carryPrev;
                    carryPrev = cj * t - sj * carryPrev;
                }
                Zl[lane + ZS * (l - 1)] = carryPrev;
            }
            WD(l, RD(l) - p);
            WE(l - 1, g);
            goto L90;
L130:
            WD(l, p);
            l = l - 1;
            if (l >= lend) goto L90;
            goto L140;
        }
L140:
        if (iscale == 1) {
            float mul = anorm / ssfmax_;
            if (lane + 1 >= lsv && lane + 1 <= lendsv) dr *= mul;
            if (lane + 1 >= lsv && lane + 1 <= lendsv - 1) er *= mul;
        } else if (iscale == 2) {
            float mul = anorm / ssfmin_;
            if (lane + 1 >= lsv && lane + 1 <= lendsv) dr *= mul;
            if (lane + 1 >= lsv && lane + 1 <= lendsv - 1) er *= mul;
        }
        if (jtot < nmaxit) goto L10;
        goto L160;

L160:
        // selection sort ascending, swapping Z columns (matches dsteqr)
        for (int ii = 2; ii <= n; ++ii) {
            int ia = ii - 1, ka = ia;
            float pp = RD(ia);
            for (int jj = ii; jj <= n; ++jj) {
                float dj = RD(jj);
                if (dj < pp) { ka = jj; pp = dj; }
            }
            if (ka != ia) {
                float dia = RD(ia);
                WD(ka, dia);
                WD(ia, pp);
                if (lane < n) {
                    float t = Zl[lane + ZS * (ia - 1)];
                    Zl[lane + ZS * (ia - 1)] = Zl[lane + ZS * (ka - 1)];
                    Zl[lane + ZS * (ka - 1)] = t;
                }
            }
        }
    }

    // write d registers back to LDS for the epilogue
    if (lane < 24) dl[lane + 1] = dr;
    __syncthreads();

    // ---------- sormtr: Z := H(1)...H(n-1) * Z  (lane = column) ----------
    for (int i = n - 2; i >= 0; --i) {
        float taui = tau[i + 1];
        if (taui != 0.f && lane < n) {
            int j = lane;
            float w_ = Zl[(i + 1) + ZS * j];
            for (int r = i + 2; r < n; ++r) w_ += A[r + N24 * i] * Zl[r + ZS * j];
            Zl[(i + 1) + ZS * j] -= taui * w_;
            for (int r = i + 2; r < n; ++r) Zl[r + ZS * j] -= taui * (A[r + N24 * i] * w_);
        }
        __syncthreads();
    }

    // ---------- S, Vh, features, novelty ----------
    const int S_OFF = 0, VH_OFF = 1536, F_OFF = 38400, NOV_OFF = 41600;
    if (lane < n) {
        float ev = dl[n - lane];                   // descending
        float s0 = sqrtf(fmaxf(ev, 0.f));
        s0 = fmaxf(s0, 1e-6f);
        if (!isfinite(s0)) s0 = 1.f;
        Sarr[lane] = s0;
    }
    __syncthreads();
    if (lane < n) {
        out[S_OFF + b * 24 + lane] = Sarr[lane];
        out[NOV_OFF + b * 24 + lane] = Sarr[lane] - ema[lane];
    }
    for (int idx = lane; idx < 576; idx += 64) {   // Vh[j][i] = Z[i][23-j]
        int j = idx / 24, i2 = idx % 24;
        float vv = Zl[i2 + ZS * (23 - j)];
        if (!isfinite(vv)) vv = 0.f;
        out[VH_OFF + b * 576 + idx] = vv;
    }
    float sum_ = 0.f;
    for (int j2 = 0; j2 < n; ++j2) sum_ += Sarr[j2];
    float denom = sum_ + 1e-8f;
    if (lane < n) snorm[lane] = Sarr[lane] / denom;
    __syncthreads();
    float ent = 0.f;
    for (int j2 = 0; j2 < n; ++j2) {
        float sn2 = snorm[j2];
        ent -= sn2 * logf(fmaxf(sn2, 1e-8f));
    }
    float sumsq = 0.f, diagsq = 0.f;
    for (int j2 = 0; j2 < n; ++j2)                 // same order as r1 (i inner, j outer)
        for (int i2 = 0; i2 < n; ++i2) { float z = Zl[i2 + ZS * j2]; sumsq += z * z; }
    for (int j2 = 0; j2 < n; ++j2) { float dv = Zl[j2 + ZS * (23 - j2)]; diagsq += dv * dv; }
    float offd = fmaxf(sumsq - diagsq, 0.f);
    if (lane < n) {
        float v0 = snorm[lane]; if (!isfinite(v0)) v0 = 0.f;
        out[F_OFF + b * 50 + lane] = v0;
        float dv = Zl[lane + ZS * (23 - lane)]; if (!isfinite(dv)) dv = 0.f;
        out[F_OFF + b * 50 + 24 + lane] = dv;
    }
    if (lane == 0) {
        if (!isfinite(offd)) offd = 0.f;
        if (!isfinite(ent)) ent = 0.f;
        out[F_OFF + b * 50 + 48] = offd;
        out[F_OFF + b * 50 + 49] = ent;
    }
}

// ---------------------------------------------------------------- launch
extern "C" void kernel_launch(void* const* d_in, const int* in_sizes, int n_in,
                              void* d_out, int out_size, void* d_ws, size_t ws_size,
                              hipStream_t stream)
{
    const float* x   = (const float*)d_in[0];
    const float* w   = (const float*)d_in[1];
    const float* ema = (const float*)d_in[2];
    float* out = (float*)d_out;

    // ws layout: partial (1024*300 f64 = 2.4576 MB) | G (64*576 f32 = 147 KB)
    double* partial = (double*)d_ws;
    float* G = (float*)((char*)d_ws + (size_t)1024 * 300 * sizeof(double));

    hipLaunchKernelGGL(proj_gram_kernel, dim3(256), dim3(256), 0, stream, x, w, partial);
    hipLaunchKernelGGL(gram_reduce_kernel, dim3(64), dim3(320), 0, stream, partial, G);
    hipLaunchKernelGGL(eigh_feat_kernel, dim3(64), dim3(64), 0, stream, G, ema, out);
}

// Round 3
// 507.721 us; speedup vs baseline: 1.2963x; 1.1620x over previous
//
#include <hip/hip_runtime.h>
#include <math.h>

// SVDObserver: x (64,512,64,64) f32, w_proj (24,512) f32, ema_s (24) f32
// outputs (flat f32 concat): S (64,24) | Vh (64,24,24) | features (64,50) | novelty (64,24)
//
//  K1 proj_gram: h = W x; 4 px/thread, 8-channel double-buffered register
//     prefetch (hides ~900cyc HBM latency under 2x768cyc of FMA). FMA
//     expression text identical to r2 -> bit-identical h and G.
//  K2 gram_reduce: unchanged.
//  K3 eigh_feat: LAPACK ssyevd path, VALUES bit-identical to r2; control
//     restructured: ballot deflation scans, shfl-reduce anorm (exact fmax),
//     carried-d sweeps (fewer readlanes), branchless slartg/lapy2,
//     reduce-based selection sort (tie -> lowest index == LAPACK scan).

#define N24 24
#define ZS 25   // Zl row stride (odd -> conflict-free)

// ---------------------------------------------------------------- K1
__global__ __launch_bounds__(256) void proj_gram_kernel(
    const float* __restrict__ x, const float* __restrict__ w,
    double* __restrict__ partial)
{
    const int b   = blockIdx.x >> 2;
    const int q   = blockIdx.x & 3;
    const int tid = threadIdx.x;
    const int n0  = (q << 10) | (tid << 2);       // pixel base (4 consecutive)
    __shared__ __align__(16) float smem[24 * 512]; // 48 KB (wl, reused as hl)
    float* wl = smem;
    for (int i2 = tid; i2 < 24 * 512; i2 += 256) wl[i2] = w[i2];
    __syncthreads();

    const float* xb = x + ((size_t)b << 21) + n0; // b*512*4096 + n0
    float h[4][24];
#pragma unroll
    for (int j = 0; j < 4; ++j)
#pragma unroll
        for (int k = 0; k < 24; ++k) h[j][k] = 0.f;

    float4 cA[8];
#pragma unroll
    for (int t = 0; t < 8; ++t)
        cA[t] = *reinterpret_cast<const float4*>(xb + ((size_t)t << 12));

    for (int c = 0; c < 512; c += 8) {
        float4 cB[8];
        if (c + 8 < 512) {
#pragma unroll
            for (int t = 0; t < 8; ++t)
                cB[t] = *reinterpret_cast<const float4*>(xb + ((size_t)(c + 8 + t) << 12));
        }
#pragma unroll
        for (int sub = 0; sub < 2; ++sub) {
            const float4 a0 = cA[sub * 4 + 0];
            const float4 a1 = cA[sub * 4 + 1];
            const float4 a2 = cA[sub * 4 + 2];
            const float4 a3 = cA[sub * 4 + 3];
            const int cc = c + sub * 4;
#pragma unroll
            for (int k = 0; k < 24; ++k) {
                const float4 wv = *reinterpret_cast<const float4*>(&wl[k * 512 + cc]);
                h[0][k] += wv.x * a0.x + wv.y * a1.x + wv.z * a2.x + wv.w * a3.x;
                h[1][k] += wv.x * a0.y + wv.y * a1.y + wv.z * a2.y + wv.w * a3.y;
                h[2][k] += wv.x * a0.z + wv.y * a1.z + wv.z * a2.z + wv.w * a3.z;
                h[3][k] += wv.x * a0.w + wv.y * a1.w + wv.z * a2.w + wv.w * a3.w;
            }
        }
#pragma unroll
        for (int t = 0; t < 8; ++t) cA[t] = cB[t];
    }
    __syncthreads();           // everyone done reading wl

    float* hl = smem;          // reuse: 256 px * 24 floats = 24 KB
    const int s_own = tid >> 6, l64 = tid & 63;
    for (int s2 = 0; s2 < 4; ++s2) {
        if (s_own == s2) {
#pragma unroll
            for (int j = 0; j < 4; ++j)
#pragma unroll
                for (int k = 0; k < 24; ++k)
                    hl[((l64 << 2) + j) * 24 + k] = h[j][k];
        }
        __syncthreads();
        for (int p = tid; p < 300; p += 256) {
            int k = 0, pp = p;
            while (pp >= 24 - k) { pp -= 24 - k; ++k; }
            int m = k + pp;
            double acc = 0.0;
            for (int i2 = 0; i2 < 256; ++i2)
                acc += (double)hl[i2 * 24 + k] * (double)hl[i2 * 24 + m];
            partial[((size_t)(b * 16 + (q << 2) + s2)) * 300 + p] = acc;
        }
        __syncthreads();
    }
}

// ---------------------------------------------------------------- K2
__global__ __launch_bounds__(320) void gram_reduce_kernel(
    const double* __restrict__ partial, float* __restrict__ G)
{
    const int b = blockIdx.x;
    const int p = threadIdx.x;
    if (p >= 300) return;
    int k = 0, pp = p;
    while (pp >= 24 - k) { pp -= 24 - k; ++k; }
    int m = k + pp;
    double acc = 0.0;
    for (int t = 0; t < 16; ++t)
        acc += partial[((size_t)(b * 16 + t)) * 300 + p];
    float v = (float)acc;
    G[b * 576 + k * 24 + m] = v;
    G[b * 576 + m * 24 + k] = v;   // exactly symmetric
}

// ------------------------------------------------------- LAPACK helpers
__device__ __forceinline__ float rlf(float v, int l) {
    return __int_as_float(__builtin_amdgcn_readlane(__float_as_int(v), l));
}

__device__ __forceinline__ float lapy2f(float xx, float yy) {
#pragma clang fp contract(off)
    float xa = fabsf(xx), ya = fabsf(yy);
    float w = fmaxf(xa, ya), z = fminf(xa, ya);
    float q = z / w;
    float res = w * sqrtf(1.f + q * q);
    return (z == 0.f) ? w : res;
}

__device__ __forceinline__ void slartg_(float f, float g, float& c, float& s, float& r) {
#pragma clang fp contract(off)
    float f1 = fabsf(f), g1 = fabsf(g);
    const float rtmin_ = 0x1p-63f;          // sqrt(safmin)
    const float rtmax_ = 1.8446743e+19f;    // ~sqrt(safmax)
    bool inr = (f1 > rtmin_) && (f1 < rtmax_) && (g1 > rtmin_) && (g1 < rtmax_);
    if (__builtin_expect(!inr && f != 0.f && g != 0.f, 0)) {
        float u = fminf(3.4028235e+38f, fmaxf(0x1p-126f, fmaxf(f1, g1)));
        float fs = f / u, gs = g / u;
        float d = sqrtf(fs * fs + gs * gs);
        float p = 1.f / d;
        c = fabsf(fs) * p;
        s = gs * copysignf(p, f);
        r = copysignf(d, f) * u;
    } else {
        float d = sqrtf(f * f + g * g);
        float p = 1.f / d;
        float cN = f1 * p;
        float sN = g * copysignf(p, f);
        float rN = copysignf(d, f);
        bool gz = (g == 0.f), fz = (f == 0.f);
        c = gz ? 1.f : (fz ? 0.f : cN);
        s = gz ? 0.f : (fz ? copysignf(1.f, g) : sN);
        r = gz ? f   : (fz ? g1 : rN);
    }
}

__device__ __forceinline__ void slaev2_(float a, float b, float cc,
                                        float& rt1, float& rt2, float& cs1, float& sn1) {
#pragma clang fp contract(off)
    float sm = a + cc, df = a - cc, adf = fabsf(df);
    float tb = b + b, ab = fabsf(tb);
    float acmx, acmn;
    if (fabsf(a) > fabsf(cc)) { acmx = a; acmn = cc; } else { acmx = cc; acmn = a; }
    float rt;
    if (adf > ab)      { float q = ab / adf; rt = adf * sqrtf(1.f + q * q); }
    else if (adf < ab) { float q = adf / ab; rt = ab * sqrtf(1.f + q * q); }
    else               rt = ab * sqrtf(2.f);
    int sgn1;
    if (sm < 0.f)      { rt1 = 0.5f * (sm - rt); sgn1 = -1; rt2 = (acmx / rt1) * acmn - (b / rt1) * b; }
    else if (sm > 0.f) { rt1 = 0.5f * (sm + rt); sgn1 =  1; rt2 = (acmx / rt1) * acmn - (b / rt1) * b; }
    else               { rt1 = 0.5f * rt; rt2 = -0.5f * rt; sgn1 = 1; }
    float cs; int sgn2;
    if (df >= 0.f) { cs = df + rt; sgn2 = 1; } else { cs = df - rt; sgn2 = -1; }
    float acs = fabsf(cs);
    if (acs > ab) { float ct = -tb / cs; sn1 = 1.f / sqrtf(1.f + ct * ct); cs1 = ct * sn1; }
    else {
        if (ab == 0.f) { cs1 = 1.f; sn1 = 0.f; }
        else { float tn = -cs / tb; cs1 = 1.f / sqrtf(1.f + tn * tn); sn1 = tn * cs1; }
    }
    if (sgn1 == sgn2) { float tn = cs1; cs1 = -sn1; sn1 = tn; }
}

// d/e register accessors (1-based index j, owner lane j-1)
#define RD(j)   rlf(dr, (j) - 1)
#define RE(j)   rlf(er, (j) - 1)
#define WD(j,v) { float _v = (v); int _j = (j) - 1; dr = (lane == _j) ? _v : dr; }
#define WE(j,v) { float _v = (v); int _j = (j) - 1; er = (lane == _j) ? _v : er; }

// ---------------------------------------------------------------- K3
__global__ __launch_bounds__(64) void eigh_feat_kernel(
    const float* __restrict__ G, const float* __restrict__ ema,
    float* __restrict__ out)
{
#pragma clang fp contract(off)
    const int b = blockIdx.x;
    const int lane = threadIdx.x;
    const int n = N24;

    __shared__ float A[N24 * N24];      // col-major A[i + 24*j]
    __shared__ float Zl[N24 * ZS];      // row i, col j at Zl[i + ZS*j]
    __shared__ float dl[N24 + 1], el[N24 + 1], tau[N24 + 1];
    __shared__ float hv[N24], hw[N24];
    __shared__ float Sarr[N24], snorm[N24];

    for (int idx = lane; idx < n * n; idx += 64) A[idx] = G[(size_t)b * n * n + idx];
    __syncthreads();

    // ---------- ssytd2 (lower) ---------- (unchanged arithmetic)
    for (int i = 0; i < n - 1; ++i) {
        const int mlen = n - 1 - i;
        float alpha = A[(i + 1) + N24 * i];
        float ss = 0.f;
        for (int r = i + 2; r < n; ++r) { float t = A[r + N24 * i]; ss += t * t; }
        float xnorm = sqrtf(ss);
        if (xnorm == 0.f) {
            if (lane == 0) { tau[i + 1] = 0.f; el[i + 1] = alpha; dl[i + 1] = A[i + N24 * i]; }
            __syncthreads();
            continue;
        }
        float beta = -copysignf(lapy2f(alpha, xnorm), alpha);
        float taui = (beta - alpha) / beta;
        float scal = 1.f / (alpha - beta);
        if (lane == 0) { tau[i + 1] = taui; el[i + 1] = beta; }
        __syncthreads();
        if (lane >= i + 2 && lane < n) A[lane + N24 * i] *= scal;
        __syncthreads();
        if (lane < mlen) hv[lane] = (lane == 0) ? 1.f : A[(i + 1 + lane) + N24 * i];
        __syncthreads();
        if (lane < mlen) {                      // x = tau * Asub * v
            float acc = 0.f;
            int gr = i + 1 + lane;
            for (int c2 = 0; c2 < mlen; ++c2) {
                int gc = i + 1 + c2;
                float av = (gr >= gc) ? A[gr + N24 * gc] : A[gc + N24 * gr];
                acc += av * hv[c2];
            }
            hw[lane] = taui * acc;
        }
        __syncthreads();
        float dot = 0.f;
        for (int r2 = 0; r2 < mlen; ++r2) dot += hw[r2] * hv[r2];
        float alpha2 = -0.5f * taui * dot;
        __syncthreads();
        if (lane < mlen) hw[lane] += alpha2 * hv[lane];
        __syncthreads();
        if (lane < mlen) {                      // rank-2 update, lower triangle
            for (int c2 = 0; c2 <= lane; ++c2)
                A[(i + 1 + lane) + N24 * (i + 1 + c2)] -= hv[lane] * hw[c2] + hw[lane] * hv[c2];
        }
        __syncthreads();
        if (lane == 0) dl[i + 1] = A[i + N24 * i];
        __syncthreads();
    }
    if (lane == 0) dl[n] = A[(n - 1) + N24 * (n - 1)];
    __syncthreads();

    // ---------- ssteqr('I'), state in registers ----------
    for (int idx = lane; idx < N24 * ZS; idx += 64) Zl[idx] = 0.f;
    __syncthreads();
    if (lane < n) Zl[lane + ZS * lane] = 1.f;
    __syncthreads();

    float dr = (lane < 24) ? dl[lane + 1] : 0.f;   // lane i holds d[i+1]
    float er = (lane < 23) ? el[lane + 1] : 0.f;   // lane i holds e[i+1]
    float wcr = 0.f, wsr = 0.f;

    {
        const float eps_    = 0x1p-24f;
        const float eps2_   = 0x1p-48f;
        const float safmin_ = 0x1p-126f;
        const float ssfmax_ = 3.0744573e+18f;
        const float ssfmin_ = 0x1p-15f;
        const int nmaxit = n * 30;
        int jtot = 0, l1 = 1;
        int l = 0, lsv = 0, lend = 0, lendsv = 0, mb = 0, iscale = 0;
        float anorm = 0.f, p = 0.f, g = 0.f, r_ = 0.f, c_ = 0.f, s_ = 0.f, f_ = 0.f, b_ = 0.f;
        float rt1 = 0.f, rt2 = 0.f, cc = 0.f, sn = 0.f;
        int m_ = 0, i_ = 0, j_ = 0;

L10:
        if (l1 > n) goto L160;
        if (l1 > 1) WE(l1 - 1, 0.f);
        {   // ballot deflation scan over m in [l1, n-1]
            float dnx = __shfl_down(dr, 1, 64);
            float ae = fabsf(er);
            bool inr = (lane >= l1 - 1) && (lane <= n - 2);
            bool t0 = inr && (ae == 0.f);
            bool t1 = inr && (ae <= (sqrtf(fabsf(dr)) * sqrtf(fabsf(dnx))) * eps_);
            unsigned long long msk0 = __ballot(t0);
            unsigned long long mskc = msk0 | __ballot(t1);
            if (mskc) {
                int bit = __builtin_ctzll(mskc);
                m_ = bit + 1;
                bool wasz = (msk0 >> bit) & 1ull;
                if (!wasz) WE(m_, 0.f);
            } else m_ = n;
        }
        l = l1; lsv = l; lend = m_; lendsv = lend; l1 = m_ + 1;
        if (lend == l) goto L10;

        {   // anorm = max |d[l..lend]|, |e[l..lend-1]|  (exact fmax reduce)
            bool ind = (lane >= l - 1) && (lane <= lend - 1);
            bool ine = (lane >= l - 1) && (lane <= lend - 2);
            float v = fmaxf(ind ? fabsf(dr) : 0.f, ine ? fabsf(er) : 0.f);
            for (int off = 32; off; off >>= 1) v = fmaxf(v, __shfl_xor(v, off, 64));
            anorm = v;
        }
        iscale = 0;
        if (anorm == 0.f) goto L10;
        if (anorm > ssfmax_) {
            iscale = 1;
            float mul = ssfmax_ / anorm;
            if (lane + 1 >= l && lane + 1 <= lend) dr *= mul;
            if (lane + 1 >= l && lane + 1 <= lend - 1) er *= mul;
        } else if (anorm < ssfmin_) {
            iscale = 2;
            float mul = ssfmin_ / anorm;
            if (lane + 1 >= l && lane + 1 <= lend) dr *= mul;
            if (lane + 1 >= l && lane + 1 <= lend - 1) er *= mul;
        }
        if (fabsf(RD(lend)) < fabsf(RD(l))) { lend = lsv; l = lendsv; }

        if (lend > l) {
            // ------------- QL -------------
L40:
            if (l != lend) {
                float dnx = __shfl_down(dr, 1, 64);
                bool inr = (lane >= l - 1) && (lane <= lend - 2);
                bool t = inr && (er * er <= (eps2_ * fabsf(dr)) * fabsf(dnx) + safmin_);
                unsigned long long msk = __ballot(t);
                m_ = msk ? (__builtin_ctzll(msk) + 1) : lend;
            } else m_ = lend;
            if (m_ < lend) WE(m_, 0.f);
            mb = m_;
            p = RD(l);
            if (mb == l) goto L80;
            if (mb == l + 1) {                      // 2x2
                slaev2_(RD(l), RE(l), RD(l + 1), rt1, rt2, cc, sn);
                if (lane < n) {
                    float z1 = Zl[lane + ZS * l];
                    float z0 = Zl[lane + ZS * (l - 1)];
                    Zl[lane + ZS * l]       = cc * z1 - sn * z0;
                    Zl[lane + ZS * (l - 1)] = sn * z1 + cc * z0;
                }
                WD(l, rt1); WD(l + 1, rt2); WE(l, 0.f);
                l = l + 2;
                if (l <= lend) goto L40;
                goto L140;
            }
            if (jtot == nmaxit) goto L140;
            jtot = jtot + 1;
            {
                float dmb = RD(mb);
                g = (RD(l + 1) - p) / (2.f * RE(l));
                r_ = lapy2f(g, 1.f);
                g = dmb - p + (RE(l) / (g + copysignf(r_, g)));
                s_ = 1.f; c_ = 1.f; p = 0.f;
                float dcar = dmb;                   // d[i_+1] carry
                for (i_ = mb - 1; i_ >= l; --i_) {
                    float ei = RE(i_);
                    float di = RD(i_);
                    f_ = s_ * ei;
                    b_ = c_ * ei;
                    slartg_(g, f_, c_, s_, r_);
                    er = ((i_ != mb - 1) && (lane == i_)) ? r_ : er;   // WE(i_+1)
                    g = dcar - p;
                    r_ = (di - g) * s_ + 2.f * c_ * b_;
                    p = s_ * r_;
                    dr = (lane == i_) ? (g + p) : dr;                  // WD(i_+1)
                    g = c_ * r_ - b_;
                    bool w3 = (lane == i_ - 1);
                    wcr = w3 ? c_ : wcr;
                    wsr = w3 ? -s_ : wsr;
                    dcar = di;
                }
                if (lane < n) {                     // dlasr 'R','V','B'
                    float carry = Zl[lane + ZS * (mb - 1)];
                    for (j_ = mb - 1; j_ >= l; --j_) {
                        float cj = rlf(wcr, j_ - 1), sj = rlf(wsr, j_ - 1);
                        float prev = Zl[lane + ZS * (j_ - 1)];
                        Zl[lane + ZS * j_] = cj * carry - sj * prev;
                        carry = sj * carry + cj * prev;
                    }
                    Zl[lane + ZS * (l - 1)] = carry;
                }
                WD(l, dcar - p);                    // dcar == RD(l) pre-write
                WE(l, g);
            }
            goto L40;
L80:
            WD(l, p);
            l = l + 1;
            if (l <= lend) goto L40;
            goto L140;
        } else {
            // ------------- QR -------------
L90:
            if (l != lend) {
                float epu = __shfl_up(er, 1, 64);
                float dup = __shfl_up(dr, 1, 64);
                bool inr = (lane >= lend) && (lane <= l - 1);
                bool t = inr && (epu * epu <= (eps2_ * fabsf(dr)) * fabsf(dup) + safmin_);
                unsigned long long msk = __ballot(t);
                if (msk) {
                    // highest set bit <= l-1 (mask already restricted)
                    m_ = 63 - __builtin_clzll(msk) + 1;
                } else m_ = lend;
            } else m_ = lend;
            if (m_ > lend) WE(m_ - 1, 0.f);
            mb = m_;
            p = RD(l);
            if (mb == l) goto L130;
            if (mb == l - 1) {                      // 2x2
                slaev2_(RD(l - 1), RE(l - 1), RD(l), rt1, rt2, cc, sn);
                if (lane < n) {
                    float z1 = Zl[lane + ZS * (l - 1)];
                    float z0 = Zl[lane + ZS * (l - 2)];
                    Zl[lane + ZS * (l - 1)] = cc * z1 - sn * z0;
                    Zl[lane + ZS * (l - 2)] = sn * z1 + cc * z0;
                }
                WD(l - 1, rt1); WD(l, rt2); WE(l - 1, 0.f);
                l = l - 2;
                if (l >= lend) goto L90;
                goto L140;
            }
            if (jtot == nmaxit) goto L140;
            jtot = jtot + 1;
            {
                float dmb = RD(mb);
                g = (RD(l - 1) - p) / (2.f * RE(l - 1));
                r_ = lapy2f(g, 1.f);
                g = dmb - p + (RE(l - 1) / (g + copysignf(r_, g)));
                s_ = 1.f; c_ = 1.f; p = 0.f;
                float dcar = dmb;                   // d[i_] carry
                for (i_ = mb; i_ <= l - 1; ++i_) {
                    float ei = RE(i_);
                    float dnx = RD(i_ + 1);
                    f_ = s_ * ei;
                    b_ = c_ * ei;
                    slartg_(g, f_, c_, s_, r_);
                    er = ((i_ != mb) && (lane == i_ - 2)) ? r_ : er;   // WE(i_-1)
                    g = dcar - p;
                    r_ = (dnx - g) * s_ + 2.f * c_ * b_;
                    p = s_ * r_;
                    dr = (lane == i_ - 1) ? (g + p) : dr;              // WD(i_)
                    g = c_ * r_ - b_;
                    bool w3 = (lane == i_ - 1);
                    wcr = w3 ? c_ : wcr;
                    wsr = w3 ? s_ : wsr;
                    dcar = dnx;
                }
                if (lane < n) {                     // dlasr 'R','V','F'
                    float carryPrev = Zl[lane + ZS * (mb - 1)];
                    for (j_ = mb; j_ <= l - 1; ++j_) {
                        float cj = rlf(wcr, j_ - 1), sj = rlf(wsr, j_ - 1);
                        float t = Zl[lane + ZS * j_];
                        Zl[lane + ZS * (j_ - 1)] = sj * t + cj * carryPrev;
                        carryPrev = cj * t - sj * carryPrev;
                    }
                    Zl[lane + ZS * (l - 1)] = carryPrev;
                }
                WD(l, dcar - p);                    // dcar == RD(l) pre-write
                WE(l - 1, g);
            }
            goto L90;
L130:
            WD(l, p);
            l = l - 1;
            if (l >= lend) goto L90;
            goto L140;
        }
L140:
        if (iscale == 1) {
            float mul = anorm / ssfmax_;
            if (lane + 1 >= lsv && lane + 1 <= lendsv) dr *= mul;
            if (lane + 1 >= lsv && lane + 1 <= lendsv - 1) er *= mul;
        } else if (iscale == 2) {
            float mul = anorm / ssfmin_;
            if (lane + 1 >= lsv && lane + 1 <= lendsv) dr *= mul;
            if (lane + 1 >= lsv && lane + 1 <= lendsv - 1) er *= mul;
        }
        if (jtot < nmaxit) goto L10;
        goto L160;

L160:
        // selection sort ascending via min+index reduce (tie -> lowest index)
        for (int ii = 2; ii <= n; ++ii) {
            int ia = ii - 1;
            float val = (lane >= ii - 2 && lane <= n - 1) ? dr : __builtin_inff();
            int idx = lane + 1;
            for (int off = 32; off; off >>= 1) {
                float v2 = __shfl_xor(val, off, 64);
                int   i2 = __shfl_xor(idx, off, 64);
                bool take = (v2 < val) || ((v2 == val) && (i2 < idx));
                val = take ? v2 : val;
                idx = take ? i2 : idx;
            }
            int ka = idx;      // uniform
            float pp = val;
            if (ka != ia) {
                float dia = RD(ia);
                WD(ka, dia);
                WD(ia, pp);
                if (lane < n) {
                    float t = Zl[lane + ZS * (ia - 1)];
                    Zl[lane + ZS * (ia - 1)] = Zl[lane + ZS * (ka - 1)];
                    Zl[lane + ZS * (ka - 1)] = t;
                }
            }
        }
    }

    // write d registers back to LDS for the epilogue
    if (lane < 24) dl[lane + 1] = dr;
    __syncthreads();

    // ---------- sormtr: Z := H(1)...H(n-1) * Z  (lane = column) ----------
    for (int i = n - 2; i >= 0; --i) {
        float taui = tau[i + 1];
        if (taui != 0.f && lane < n) {
            int j = lane;
            float w_ = Zl[(i + 1) + ZS * j];
            for (int r = i + 2; r < n; ++r) w_ += A[r + N24 * i] * Zl[r + ZS * j];
            Zl[(i + 1) + ZS * j] -= taui * w_;
            for (int r = i + 2; r < n; ++r) Zl[r + ZS * j] -= taui * (A[r + N24 * i] * w_);
        }
        __syncthreads();
    }

    // ---------- S, Vh, features, novelty ----------
    const int S_OFF = 0, VH_OFF = 1536, F_OFF = 38400, NOV_OFF = 41600;
    if (lane < n) {
        float ev = dl[n - lane];                   // descending
        float s0 = sqrtf(fmaxf(ev, 0.f));
        s0 = fmaxf(s0, 1e-6f);
        if (!isfinite(s0)) s0 = 1.f;
        Sarr[lane] = s0;
    }
    __syncthreads();
    if (lane < n) {
        out[S_OFF + b * 24 + lane] = Sarr[lane];
        out[NOV_OFF + b * 24 + lane] = Sarr[lane] - ema[lane];
    }
    for (int idx = lane; idx < 576; idx += 64) {   // Vh[j][i] = Z[i][23-j]
        int j = idx / 24, i2 = idx % 24;
        float vv = Zl[i2 + ZS * (23 - j)];
        if (!isfinite(vv)) vv = 0.f;
        out[VH_OFF + b * 576 + idx] = vv;
    }
    float sum_ = 0.f;
    for (int j2 = 0; j2 < n; ++j2) sum_ += Sarr[j2];
    float denom = sum_ + 1e-8f;
    if (lane < n) snorm[lane] = Sarr[lane] / denom;
    __syncthreads();
    float ent = 0.f;
    for (int j2 = 0; j2 < n; ++j2) {
        float sn2 = snorm[j2];
        ent -= sn2 * logf(fmaxf(sn2, 1e-8f));
    }
    float sumsq = 0.f, diagsq = 0.f;
    for (int j2 = 0; j2 < n; ++j2)
        for (int i2 = 0; i2 < n; ++i2) { float z = Zl[i2 + ZS * j2]; sumsq += z * z; }
    for (int j2 = 0; j2 < n; ++j2) { float dv = Zl[j2 + ZS * (23 - j2)]; diagsq += dv * dv; }
    float offd = fmaxf(sumsq - diagsq, 0.f);
    if (lane < n) {
        float v0 = snorm[lane]; if (!isfinite(v0)) v0 = 0.f;
        out[F_OFF + b * 50 + lane] = v0;
        float dv = Zl[lane + ZS * (23 - lane)]; if (!isfinite(dv)) dv = 0.f;
        out[F_OFF + b * 50 + 24 + lane] = dv;
    }
    if (lane == 0) {
        if (!isfinite(offd)) offd = 0.f;
        if (!isfinite(ent)) ent = 0.f;
        out[F_OFF + b * 50 + 48] = offd;
        out[F_OFF + b * 50 + 49] = ent;
    }
}

// ---------------------------------------------------------------- launch
extern "C" void kernel_launch(void* const* d_in, const int* in_sizes, int n_in,
                              void* d_out, int out_size, void* d_ws, size_t ws_size,
                              hipStream_t stream)
{
    const float* x   = (const float*)d_in[0];
    const float* w   = (const float*)d_in[1];
    const float* ema = (const float*)d_in[2];
    float* out = (float*)d_out;

    double* partial = (double*)d_ws;
    float* G = (float*)((char*)d_ws + (size_t)1024 * 300 * sizeof(double));

    hipLaunchKernelGGL(proj_gram_kernel, dim3(256), dim3(256), 0, stream, x, w, partial);
    hipLaunchKernelGGL(gram_reduce_kernel, dim3(64), dim3(320), 0, stream, partial, G);
    hipLaunchKernelGGL(eigh_feat_kernel, dim3(64), dim3(64), 0, stream, G, ema, out);
}